// Round 4
// baseline (256.453 us; speedup 1.0000x reference)
//
#include <hip/hip_runtime.h>
#include <hip/hip_bf16.h>
#include <stdint.h>

// ---------- types ----------
typedef __bf16 bf16x8 __attribute__((ext_vector_type(8)));
typedef float  f32x4  __attribute__((ext_vector_type(4)));
typedef unsigned int u32x4 __attribute__((ext_vector_type(4)));

__device__ __forceinline__ unsigned short f2bf(float x) {
    union { float f; unsigned u; } v; v.f = x;
    unsigned r = v.u + 0x7fffu + ((v.u >> 16) & 1u);   // RNE
    return (unsigned short)(r >> 16);
}

__device__ __forceinline__ float bf2f(unsigned short b) {
    union { unsigned u; float f; } v; v.u = ((unsigned)b) << 16; return v.f;
}

__device__ __forceinline__ void async16(const void* g, void* l) {
    __builtin_amdgcn_global_load_lds(
        (const __attribute__((address_space(1))) void*)g,
        (__attribute__((address_space(3))) void*)l,
        16, 0, 0);
}

// =====================================================================
// 256x256 8-phase QKV GEMM (T1+T2+T3+T4+T5).
// A: M x K row-major bf16 (lda), Bt: N x K row-major (ldb), K multiple of 64,
// nt = K/64 even, M%256==0, N%256==0.
// C[m][n] = sum_k A[m][k]*Bt[n][k]  (bf16 out, no scale).
// Tiles with n0 >= nsplit are stored TRANSPOSED into VtOut (V fold).
// 8 waves (2M x 4N), per-wave output 128x64. LDS 128 KiB: 2 buffers x
// (A 256x64 | B 256x64). Half-tile = 128x64 = 16 KiB = 512 thr x 2 x 16 B.
// LDS swizzle: 16B-slot s of row r holds logical slot s^(r&7); staged via
// pre-swizzled GLOBAL source (linear LDS dest), read with the same XOR.
// Schedule per iteration (tiles t=buf0 / t+1=buf1), 1 half-tile stage/phase:
//  P1 A0(t+1)  P2 A1(t+1)  P3 B0(t+2)  P4 B1(t+2)+vmcnt(4)
//  P5 A0(t+2)  P6 A1(t+2)  P7 B0(t+3)  P8 B1(t+3)+vmcnt(4)
// Every stage targets a slot freed by an earlier end-of-phase barrier; every
// vmcnt(4) leaves exactly the 2 newest half-tiles (4 loads) in flight.
// Grid swizzle: 96 blocks/z -> 8 XCD chunks of (4 bm x 3 bn); bijective.
// =====================================================================
__global__ __launch_bounds__(512, 2) void gemm256_qkv(
    const unsigned short* __restrict__ A,
    const unsigned short* __restrict__ Bt,
    unsigned short* __restrict__ C,
    unsigned short* __restrict__ VtOut,
    int K, int lda, int ldb, int ldc, int ldvt, int nsplit,
    long long sA, long long sC, long long sVt)
{
    __shared__ __align__(16) char LDS[131072];
    // T1: XCD-chunked bijective remap (gridDim.x==12, gridDim.y==8 assumed)
    const int o = blockIdx.y * gridDim.x + blockIdx.x;   // 0..95, x-fastest
    const int xc = o & 7, rr_ = o >> 3;                  // chunk, 0..11
    const int bn = (xc & 3) * 3 + (rr_ % 3);
    const int bm = (xc >> 2) * 4 + (rr_ / 3);
    const int bz = blockIdx.z;
    const int m0 = bm * 256, n0 = bn * 256;
    const int nt = K >> 6;

    const unsigned short* Ab = A + (long long)bz * sA + (long long)m0 * lda;
    const unsigned short* Bb = Bt + (long long)n0 * ldb;

    const int tid = threadIdx.x;
    const int w = tid >> 6, l = tid & 63;
    const int wr = w >> 2, wc = w & 3;
    const int lrow = l & 15, quad = l >> 4;

    // staging (per-thread): row sr, physical slot tid&7, logical slot ssl
    const int sr  = tid >> 3;
    const int ssl = (tid & 7) ^ (sr & 7);

    // fragment-read offsets (bytes within a buffer)
    const int sw = lrow & 7;
    const unsigned slot0 = (unsigned)((quad ^ sw) * 16);
    const unsigned slot1 = (unsigned)(((4 + quad) ^ sw) * 16);
    const unsigned aB = (unsigned)(wr * 16384 + lrow * 128);
    const unsigned bB = (unsigned)(32768 + (wc >> 1) * 16384 + ((wc & 1) * 64 + lrow) * 128);

    f32x4 acc[8][4] = {};

    // stage one half-tile: piece 0=A0,1=A1,2=B0,3=B1 of K-tile t
    auto STAGE = [&](int t, int piece) {
        if (t >= nt) return;
        char* dst = LDS + ((t & 1) << 16) + (piece << 14) + tid * 16;
        const unsigned short* G = (piece < 2) ? Ab : Bb;
        const int ld = (piece < 2) ? lda : ldb;
        const unsigned short* g = G + (long long)((piece & 1) * 128 + sr) * ld + (t << 6) + ssl * 8;
        async16(g, dst);
        async16(g + (long long)64 * ld, dst + 8192);
    };

    auto LDA4 = [&](bf16x8 (&a)[4][2], unsigned cb, int mh) {
        const unsigned base = cb + aB + (unsigned)(mh * 8192);
#pragma unroll
        for (int i = 0; i < 4; i++) {
            a[i][0] = *(const bf16x8*)(LDS + base + i * 2048 + slot0);
            a[i][1] = *(const bf16x8*)(LDS + base + i * 2048 + slot1);
        }
    };
    auto LDB2 = [&](bf16x8 (&b)[2][2], unsigned cb, int nh) {
        const unsigned base = cb + bB + (unsigned)(nh * 4096);
#pragma unroll
        for (int j = 0; j < 2; j++) {
            b[j][0] = *(const bf16x8*)(LDS + base + j * 2048 + slot0);
            b[j][1] = *(const bf16x8*)(LDS + base + j * 2048 + slot1);
        }
    };
    auto MMQ = [&](bf16x8 (&a)[4][2], bf16x8 (&b)[2][2], int mh, int nh) {
#pragma unroll
        for (int i = 0; i < 4; i++)
#pragma unroll
            for (int j = 0; j < 2; j++)
#pragma unroll
                for (int ks = 0; ks < 2; ks++)
                    acc[mh * 4 + i][nh * 2 + j] = __builtin_amdgcn_mfma_f32_16x16x32_bf16(
                        a[i][ks], b[j][ks], acc[mh * 4 + i][nh * 2 + j], 0, 0, 0);
    };

    // rule #18 hardening: pin MFMA after the lgkmcnt wait with sched_barrier(0)
#define MIDBAR() do { __builtin_amdgcn_s_barrier(); \
                      asm volatile("s_waitcnt lgkmcnt(0)" ::: "memory"); \
                      __builtin_amdgcn_sched_barrier(0); } while (0)
#define ENDBAR() do { asm volatile("s_waitcnt lgkmcnt(0)" ::: "memory"); \
                      __builtin_amdgcn_s_barrier(); } while (0)
#define VM4()    asm volatile("s_waitcnt vmcnt(4)" ::: "memory")
#define VM0()    asm volatile("s_waitcnt vmcnt(0)" ::: "memory")

    // prologue: tile0 complete + B halves of tile1 in flight
    STAGE(0, 0); STAGE(0, 1); STAGE(0, 2); STAGE(0, 3);
    STAGE(1, 2); STAGE(1, 3);
    VM4();                       // tile0's 8 loads landed; B(1) (4 loads) in flight
    ENDBAR();

    for (int t = 0; t < nt; t += 2) {
        bf16x8 a[4][2], b0[2][2], b1[2][2];
        // -------- tile t in buf0 --------
        // P1: quadrant (m0..3 x n0..1)
        LDA4(a, 0, 0); LDB2(b0, 0, 0);
        STAGE(t + 1, 0);
        MIDBAR(); __builtin_amdgcn_s_setprio(1); MMQ(a, b0, 0, 0); __builtin_amdgcn_s_setprio(0); ENDBAR();
        // P2: (m0..3 x n2..3)
        LDB2(b1, 0, 1);
        STAGE(t + 1, 1);
        MIDBAR(); __builtin_amdgcn_s_setprio(1); MMQ(a, b1, 0, 1); __builtin_amdgcn_s_setprio(0); ENDBAR();
        // P3: (m4..7 x n0..1)
        LDA4(a, 0, 1);
        STAGE(t + 2, 2);
        MIDBAR(); __builtin_amdgcn_s_setprio(1); MMQ(a, b0, 1, 0); __builtin_amdgcn_s_setprio(0); ENDBAR();
        // P4: (m4..7 x n2..3) + vmcnt
        STAGE(t + 2, 3);
        MIDBAR(); __builtin_amdgcn_s_setprio(1); MMQ(a, b1, 1, 1); __builtin_amdgcn_s_setprio(0);
        if (t + 2 < nt) { VM4(); } else { VM0(); }
        ENDBAR();
        // -------- tile t+1 in buf1 --------
        // P5
        LDA4(a, 65536, 0); LDB2(b0, 65536, 0);
        STAGE(t + 2, 0);
        MIDBAR(); __builtin_amdgcn_s_setprio(1); MMQ(a, b0, 0, 0); __builtin_amdgcn_s_setprio(0); ENDBAR();
        // P6
        LDB2(b1, 65536, 1);
        STAGE(t + 2, 1);
        MIDBAR(); __builtin_amdgcn_s_setprio(1); MMQ(a, b1, 0, 1); __builtin_amdgcn_s_setprio(0); ENDBAR();
        // P7
        LDA4(a, 65536, 1);
        STAGE(t + 3, 2);
        MIDBAR(); __builtin_amdgcn_s_setprio(1); MMQ(a, b0, 1, 0); __builtin_amdgcn_s_setprio(0); ENDBAR();
        // P8
        STAGE(t + 3, 3);
        MIDBAR(); __builtin_amdgcn_s_setprio(1); MMQ(a, b1, 1, 1); __builtin_amdgcn_s_setprio(0);
        if (t + 3 < nt) { VM4(); } else { VM0(); }
        ENDBAR();
    }
#undef MIDBAR
#undef ENDBAR
#undef VM4
#undef VM0

    // ---- V fold: store tile transposed, straight from acc ----
    if (n0 >= nsplit) {
        unsigned short* Vp = VtOut + (long long)bz * sVt;
#pragma unroll
        for (int i = 0; i < 8; i++) {
            const int trow = m0 + wr * 128 + i * 16 + quad * 4;
#pragma unroll
            for (int j = 0; j < 4; j++) {
                const int d = (n0 - nsplit) + wc * 64 + j * 16 + lrow;
                union { unsigned short u[4]; uint2 p; } o2;
#pragma unroll
                for (int r = 0; r < 4; r++) o2.u[r] = f2bf(acc[i][j][r]);
                *(uint2*)(Vp + (long long)d * ldvt + trow) = o2.p;
            }
        }
        return;
    }

    // ---- bf16 C store via per-wave LDS repack (16 rows x 144 B stride) ----
    C += (long long)bz * sC;
    char* eb = LDS + w * 2288;
    const int erow = l >> 2, ep = l & 3;
#pragma unroll
    for (int i = 0; i < 8; i++) {
#pragma unroll
        for (int j = 0; j < 4; j++)
#pragma unroll
            for (int r = 0; r < 4; r++)
                *(unsigned short*)(eb + (quad * 4 + r) * 144 + (j * 16 + lrow) * 2) =
                    f2bf(acc[i][j][r]);
        const long long gm = m0 + wr * 128 + i * 16 + erow;
#pragma unroll
        for (int c = 0; c < 2; c++) {
            u32x4 d = *(u32x4*)(eb + erow * 144 + ep * 32 + c * 16);
            *(u32x4*)(C + gm * ldc + (n0 + wc * 64 + ep * 16 + c * 8)) = d;
        }
    }
}

// ---------- bf16 B^T GEMM, 128x128 tile, BK=32, 4 waves, DOUBLE-BUFFERED ----------
// (used for S = Q K^T and O = P V)
template <typename OutT, bool CAUSAL_SKIP, bool KLIMIT, bool VFOLD>
__global__ __launch_bounds__(256, 4) void gemm_bt(
    const unsigned short* __restrict__ A,
    const unsigned short* __restrict__ Bt,
    OutT* __restrict__ C,
    unsigned short* __restrict__ VtOut,
    int M, int N, int K, int lda, int ldb, int ldc,
    int ldvt, int nsplit,
    long long sA, long long sB, long long sC, long long sVt, float scale)
{
    const int bn = blockIdx.x, bz = blockIdx.z;
    const int bm = KLIMIT ? (gridDim.y - 1 - blockIdx.y) : blockIdx.y;
    if (CAUSAL_SKIP && bn > bm) return;

    A  += (long long)bz * sA;
    Bt += (long long)bz * sB;
    C  += (long long)bz * sC;

    const int m0 = bm * 128, n0 = bn * 128;
    const int Keff = KLIMIT ? min(K, (bm + 1) * 128) : K;

    __shared__ __align__(16) unsigned short LDS[2 * 2 * 128 * 32];

    const int tid  = threadIdx.x;
    const int w    = tid >> 6, l = tid & 63;
    const int wr   = w >> 1,  wc = w & 1;
    const int lrow = l & 15,  quad = l >> 4;

    f32x4 acc[4][4] = {};

    const int rA0  = 32 * w + (l >> 2);
    const int cOff = (((l & 3) ^ ((l >> 3) & 3))) * 8;
    const unsigned short* aG0 = A  + (long long)(m0 + rA0)      * lda + cOff;
    const unsigned short* aG1 = A  + (long long)(m0 + rA0 + 16) * lda + cOff;
    const unsigned short* bG0 = Bt + (long long)(n0 + rA0)      * ldb + cOff;
    const unsigned short* bG1 = Bt + (long long)(n0 + rA0 + 16) * ldb + cOff;
    unsigned short* aL = &LDS[(2 * w) * 512 + l * 8];
    unsigned short* bL = aL + 4096;

    const int sl = (lrow >> 1) & 3;

    async16(aG0, aL);
    async16(aG1, aL + 512);
    async16(bG0, bL);
    async16(bG1, bL + 512);

    for (int k0 = 0; k0 < Keff; k0 += 32) {
        const int cur = ((k0 >> 5) & 1) * 8192;
        __syncthreads();

        if (k0 + 32 < Keff) {
            const int nxt = cur ^ 8192;
            async16(aG0 + k0 + 32, aL + nxt);
            async16(aG1 + k0 + 32, aL + nxt + 512);
            async16(bG0 + k0 + 32, bL + nxt);
            async16(bG1 + k0 + 32, bL + nxt + 512);
        }

        const unsigned short* As = &LDS[cur];
        const unsigned short* Bs = &LDS[cur + 4096];
        bf16x8 af[4], bfr[4];
#pragma unroll
        for (int i = 0; i < 4; i++) {
            af[i]  = *(const bf16x8*)&As[(wr * 64 + i * 16 + lrow) * 32 + (quad ^ sl) * 8];
            bfr[i] = *(const bf16x8*)&Bs[(wc * 64 + i * 16 + lrow) * 32 + (quad ^ sl) * 8];
        }
#pragma unroll
        for (int i = 0; i < 4; i++)
#pragma unroll
            for (int j = 0; j < 4; j++)
                acc[i][j] = __builtin_amdgcn_mfma_f32_16x16x32_bf16(af[i], bfr[j], acc[i][j], 0, 0, 0);
    }

    if constexpr (VFOLD) {
        if (n0 >= nsplit) {
            unsigned short* Vp = VtOut + (long long)bz * sVt;
#pragma unroll
            for (int i = 0; i < 4; i++) {
                const int t = m0 + wr * 64 + i * 16 + quad * 4;
#pragma unroll
                for (int j = 0; j < 4; j++) {
                    const int d = (n0 - nsplit) + wc * 64 + j * 16 + lrow;
                    union { unsigned short u[4]; uint2 p; } o;
#pragma unroll
                    for (int r = 0; r < 4; r++) o.u[r] = f2bf(acc[i][j][r] * scale);
                    *(uint2*)(Vp + (long long)d * ldvt + t) = o.p;
                }
            }
            return;
        }
    }

    __syncthreads();

    char* eb = (char*)LDS + w * 2288;
    const int erow = l >> 2, ep = l & 3;

    if constexpr (sizeof(OutT) == 2) {
#pragma unroll
        for (int i = 0; i < 4; i++) {
#pragma unroll
            for (int j = 0; j < 4; j++)
#pragma unroll
                for (int r = 0; r < 4; r++)
                    *(unsigned short*)(eb + (quad * 4 + r) * 144 + (j * 16 + lrow) * 2) =
                        f2bf(acc[i][j][r] * scale);
            const long long gm = m0 + wr * 64 + i * 16 + erow;
#pragma unroll
            for (int c = 0; c < 2; c++) {
                u32x4 d = *(u32x4*)(eb + erow * 144 + ep * 32 + c * 16);
                *(u32x4*)((unsigned short*)C + gm * ldc + (n0 + wc * 64 + ep * 16 + c * 8)) = d;
            }
        }
    } else {
#pragma unroll
        for (int i = 0; i < 4; i++) {
            const long long gm = m0 + wr * 64 + i * 16 + erow;
#pragma unroll
            for (int jc = 0; jc < 2; jc++) {
#pragma unroll
                for (int jj = 0; jj < 2; jj++)
#pragma unroll
                    for (int r = 0; r < 4; r++)
                        *(float*)(eb + (quad * 4 + r) * 144 + (jj * 16 + lrow) * 4) =
                            acc[i][2 * jc + jj][r] * scale;
#pragma unroll
                for (int c = 0; c < 2; c++) {
                    f32x4 d = *(f32x4*)(eb + erow * 144 + ep * 32 + c * 16);
                    *(f32x4*)((float*)C + gm * ldc + (n0 + wc * 64 + jc * 32 + ep * 8 + c * 4)) = d;
                }
            }
        }
    }
}

// ---------- fp32 -> bf16 cast (vectorized) ----------
__global__ __launch_bounds__(256) void cast_f32_bf16(
    const float4* __restrict__ in, unsigned short* __restrict__ out, int n4)
{
    int i = blockIdx.x * 256 + threadIdx.x;
    if (i >= n4) return;
    float4 v = in[i];
    union { unsigned short u[4]; uint2 p; } o;
    o.u[0] = f2bf(v.x); o.u[1] = f2bf(v.y); o.u[2] = f2bf(v.z); o.u[3] = f2bf(v.w);
    *(uint2*)(out + (long long)i * 4) = o.p;
}

// ---------- fused W_{q,k,v} (1024x1024 fp32) -> concatenated W^T (3072 x 1024 bf16) ----------
__global__ __launch_bounds__(256) void transpose_cast_w3(
    const float* __restrict__ W0, const float* __restrict__ W1,
    const float* __restrict__ W2, unsigned short* __restrict__ out, int n)
{
    const float* in = (blockIdx.z == 0) ? W0 : (blockIdx.z == 1) ? W1 : W2;
    out += (long long)blockIdx.z * n * n;
    __shared__ float tile[32][33];
    const int tx = threadIdx.x, ty = threadIdx.y;
    const int c0 = blockIdx.x * 32, r0 = blockIdx.y * 32;
#pragma unroll
    for (int i = 0; i < 4; i++)
        tile[ty + i * 8][tx] = in[(long long)(r0 + ty + i * 8) * n + c0 + tx];
    __syncthreads();
#pragma unroll
    for (int i = 0; i < 4; i++)
        out[(long long)(c0 + ty + i * 8) * n + r0 + tx] = f2bf(tile[tx][ty + i * 8]);
}

// ---------- causal softmax: S (bf16, B*T rows of T) -> P (bf16), vectorized ----------
__global__ __launch_bounds__(256) void causal_softmax_bf16(
    const unsigned short* __restrict__ S, unsigned short* __restrict__ P, int T)
{
    const int row = blockIdx.x;
    const int t   = row & (T - 1);
    const int L   = t + 1;
    const unsigned short* s = S + (long long)row * T;
    unsigned short* p = P + (long long)row * T;
    const int tid  = threadIdx.x;
    const int base = tid * 8;

    uint4 raw = *(const uint4*)(s + base);
    unsigned rr[4] = {raw.x, raw.y, raw.z, raw.w};
    float v[8];
#pragma unroll
    for (int k = 0; k < 4; k++) {
        union { unsigned u; float f; } a, b;
        a.u = (rr[k] & 0xFFFFu) << 16;
        b.u = rr[k] & 0xFFFF0000u;
        v[2 * k] = a.f; v[2 * k + 1] = b.f;
    }
    float mx = -3.0e38f;
#pragma unroll
    for (int k = 0; k < 8; k++) {
        if (base + k >= L) v[k] = -3.0e38f;
        mx = fmaxf(mx, v[k]);
    }
#pragma unroll
    for (int off = 32; off; off >>= 1) mx = fmaxf(mx, __shfl_xor(mx, off));
    __shared__ float red[4], red2[4];
    const int wid = tid >> 6, lid = tid & 63;
    if (lid == 0) red[wid] = mx;
    __syncthreads();
    mx = fmaxf(fmaxf(red[0], red[1]), fmaxf(red[2], red[3]));

    float sum = 0.f;
#pragma unroll
    for (int k = 0; k < 8; k++) { v[k] = __expf(v[k] - mx); sum += v[k]; }
#pragma unroll
    for (int off = 32; off; off >>= 1) sum += __shfl_xor(sum, off);
    if (lid == 0) red2[wid] = sum;
    __syncthreads();
    sum = red2[0] + red2[1] + red2[2] + red2[3];
    const float inv = 1.0f / sum;

    union { unsigned short u[8]; uint4 q; } o;
#pragma unroll
    for (int k = 0; k < 8; k++) o.u[k] = f2bf(v[k] * inv);
    *(uint4*)(p + base) = o.q;
}

// ---------- launch ----------
extern "C" void kernel_launch(void* const* d_in, const int* in_sizes, int n_in,
                              void* d_out, int out_size, void* d_ws, size_t ws_size,
                              hipStream_t stream)
{
    const int B = 4, T = 2048, C = 1024, D = 1024;
    const float* x  = (const float*)d_in[0];
    const float* Wq = (const float*)d_in[1];
    const float* Wk = (const float*)d_in[2];
    const float* Wv = (const float*)d_in[3];
    float* out = (float*)d_out;
    char* ws = (char*)d_ws;

    const size_t MB = 1ull << 20;
    unsigned short* Xbf   = (unsigned short*)(ws + 0);
    unsigned short* WqkvT = (unsigned short*)(ws + 16 * MB);
    unsigned short* QK    = (unsigned short*)(ws + 22 * MB);
    unsigned short* Vt    = (unsigned short*)(ws + 54 * MB);
    unsigned short* Sbf   = (unsigned short*)(ws + 70 * MB);
    unsigned short* P     = (unsigned short*)(ws + 0);

    const long long sX  = (long long)T * C;
    const long long sQK = (long long)T * 2 * D;
    const long long sVt = (long long)D * T;
    const long long sS  = (long long)T * T;
    const long long sO  = (long long)T * D;

    // 1) x -> bf16
    {
        int n4 = B * T * C / 4;
        cast_f32_bf16<<<dim3((n4 + 255) / 256), dim3(256), 0, stream>>>(
            (const float4*)x, Xbf, n4);
    }
    // 2) fused W^T cast
    {
        dim3 g(32, 32, 3), b(32, 8);
        transpose_cast_w3<<<g, b, 0, stream>>>(Wq, Wk, Wv, WqkvT, 1024);
    }
    // 3) fused QKV GEMM (256x256 8-phase): Q,K -> QK (ldc 2048); V -> Vt transposed
    {
        dim3 g(3072 / 256, 2048 / 256, 4), b(512);
        gemm256_qkv<<<g, b, 0, stream>>>(
            Xbf, WqkvT, QK, Vt, 1024, 1024, 1024, 2048,
            /*ldvt*/ T, /*nsplit*/ 2048, sX, sQK, sVt);
    }
    // 4) S = Q K^T / 32 -> bf16, causal lower blocks only
    {
        dim3 g(2048 / 128, 2048 / 128, 4), b(256);
        gemm_bt<unsigned short, true, false, false><<<g, b, 0, stream>>>(
            QK, QK + D, Sbf, nullptr, 2048, 2048, 1024, 2 * D, 2 * D, 2048,
            0, 0, sQK, sQK, sS, 0, 0.03125f);
    }
    // 5) causal softmax (bf16 -> bf16)
    {
        causal_softmax_bf16<<<dim3(B * T), dim3(256), 0, stream>>>(Sbf, P, T);
    }
    // 6) O = P V (K clamped causally, heavy row-blocks dispatched first), fp32 out
    {
        dim3 g(1024 / 128, 2048 / 128, 4), b(256);
        gemm_bt<float, false, true, false><<<g, b, 0, stream>>>(
            P, Vt, out, nullptr, 2048, 1024, 2048, 2048, 2048, 1024,
            0, 0, sS, sVt, sO, 0, 1.0f);
    }
    (void)in_sizes; (void)n_in; (void)out_size; (void)ws_size;
}

// Round 5
// 244.751 us; speedup vs baseline: 1.0478x; 1.0478x over previous
//
#include <hip/hip_runtime.h>
#include <hip/hip_bf16.h>
#include <stdint.h>
#include <math.h>

// ---------- types ----------
typedef __bf16 bf16x8 __attribute__((ext_vector_type(8)));
typedef float  f32x4  __attribute__((ext_vector_type(4)));
typedef unsigned int u32x4 __attribute__((ext_vector_type(4)));

__device__ __forceinline__ unsigned short f2bf(float x) {
    union { float f; unsigned u; } v; v.f = x;
    unsigned r = v.u + 0x7fffu + ((v.u >> 16) & 1u);   // RNE
    return (unsigned short)(r >> 16);
}

__device__ __forceinline__ float bf2f(unsigned short b) {
    union { unsigned u; float f; } v; v.u = ((unsigned)b) << 16; return v.f;
}

__device__ __forceinline__ void async16(const void* g, void* l) {
    __builtin_amdgcn_global_load_lds(
        (const __attribute__((address_space(1))) void*)g,
        (__attribute__((address_space(3))) void*)l,
        16, 0, 0);
}

// ---------- bf16 B^T GEMM, 128x128 tile, BK=32, 4 waves, DOUBLE-BUFFERED ----------
// A: M x K (row-major bf16 bits, lda), Bt: N x K (row-major, ldb)
// C[m][n] = scale * sum_k A[m][k] * Bt[n][k]
// VFOLD: for n0 >= nsplit the 128x128 output tile is stored TRANSPOSED to
// VtOut (direct from acc; output column is lane-constant).
// KLIMIT: K clamped causally per row-block; bm reversed so heaviest blocks
// dispatch first.
// XSWZ (QKV): bijective XCD-aware remap — each XCD gets 3 contiguous bn
// columns x all bm rows. Requires gridDim.x==24.
// TRIPACK (S): gridDim.x = nb*(nb+1)/2 packed causal blocks (bn<=bm only),
// XCD-chunked (gridDim.x%8==0): consecutive triangular ids (same bm row,
// shared A-panel) stay on one XCD.
template <typename OutT, bool CAUSAL_SKIP, bool KLIMIT, bool VFOLD,
          bool XSWZ = false, bool TRIPACK = false>
__global__ __launch_bounds__(256, 4) void gemm_bt(
    const unsigned short* __restrict__ A,
    const unsigned short* __restrict__ Bt,
    OutT* __restrict__ C,
    unsigned short* __restrict__ VtOut,
    int M, int N, int K, int lda, int ldb, int ldc,
    int ldvt, int nsplit,
    long long sA, long long sB, long long sC, long long sVt, float scale)
{
    int bn, bm;
    if constexpr (TRIPACK) {
        const int o = blockIdx.x;
        const int chunk = (int)gridDim.x >> 3;          // ids per XCD
        const int t = (o & 7) * chunk + (o >> 3);       // XCD-chunked triangular id
        int r = (int)((sqrtf(8.f * (float)t + 1.f) - 1.f) * 0.5f);
        while ((r + 1) * (r + 2) / 2 <= t) r++;         // fixup (float guard)
        while (r * (r + 1) / 2 > t) r--;
        bm = r; bn = t - r * (r + 1) / 2;               // bn <= bm always
    } else if constexpr (XSWZ) {
        // original linear id o (x-fast); XCD = o & 7 on 8-XCD MI355X
        const int o = blockIdx.y * gridDim.x + blockIdx.x;
        const int x = o & 7, r = o >> 3;                // r in [0, nwg/8)
        bn = x * 3 + (r % 3);                           // 24 bn cols / 8 XCDs = 3
        bm = r / 3;
    } else {
        bn = blockIdx.x;
        bm = KLIMIT ? (gridDim.y - 1 - blockIdx.y) : blockIdx.y;
    }
    const int bz = blockIdx.z;
    if (CAUSAL_SKIP && bn > bm) return;

    A  += (long long)bz * sA;
    Bt += (long long)bz * sB;
    C  += (long long)bz * sC;

    const int m0 = bm * 128, n0 = bn * 128;
    const int Keff = KLIMIT ? min(K, (bm + 1) * 128) : K;

    // [buf][A:128x32 | B:128x32], 16 KB per buffer
    __shared__ __align__(16) unsigned short LDS[2 * 2 * 128 * 32];

    const int tid  = threadIdx.x;
    const int w    = tid >> 6, l = tid & 63;
    const int wr   = w >> 1,  wc = w & 1;
    const int lrow = l & 15,  quad = l >> 4;

    f32x4 acc[4][4] = {};

    // staging: lane l of chunk c covers row 16c + (l>>2); physical k-slot l&3
    // holds logical chunk (l&3)^((l>>3)&3) (row-pair swizzle).
    const int rA0  = 32 * w + (l >> 2);
    const int cOff = (((l & 3) ^ ((l >> 3) & 3))) * 8;
    const unsigned short* aG0 = A  + (long long)(m0 + rA0)      * lda + cOff;
    const unsigned short* aG1 = A  + (long long)(m0 + rA0 + 16) * lda + cOff;
    const unsigned short* bG0 = Bt + (long long)(n0 + rA0)      * ldb + cOff;
    const unsigned short* bG1 = Bt + (long long)(n0 + rA0 + 16) * ldb + cOff;
    unsigned short* aL = &LDS[(2 * w) * 512 + l * 8];           // A region of buf0
    unsigned short* bL = aL + 4096;                             // B region of buf0

    const int sl = (lrow >> 1) & 3;   // un-swizzle for fragment reads

    // prologue: stage tile 0 into buf 0
    async16(aG0, aL);
    async16(aG1, aL + 512);
    async16(bG0, bL);
    async16(bG1, bL + 512);

    for (int k0 = 0; k0 < Keff; k0 += 32) {
        const int cur = ((k0 >> 5) & 1) * 8192;   // element offset of current buf
        __syncthreads();                          // tile k0 ready in cur

        if (k0 + 32 < Keff) {                     // prefetch tile k0+32 into other buf
            const int nxt = cur ^ 8192;
            async16(aG0 + k0 + 32, aL + nxt);
            async16(aG1 + k0 + 32, aL + nxt + 512);
            async16(bG0 + k0 + 32, bL + nxt);
            async16(bG1 + k0 + 32, bL + nxt + 512);
        }

        const unsigned short* As = &LDS[cur];
        const unsigned short* Bs = &LDS[cur + 4096];
        bf16x8 af[4], bfr[4];
#pragma unroll
        for (int i = 0; i < 4; i++) {
            af[i]  = *(const bf16x8*)&As[(wr * 64 + i * 16 + lrow) * 32 + (quad ^ sl) * 8];
            bfr[i] = *(const bf16x8*)&Bs[(wc * 64 + i * 16 + lrow) * 32 + (quad ^ sl) * 8];
        }
#pragma unroll
        for (int i = 0; i < 4; i++)
#pragma unroll
            for (int j = 0; j < 4; j++)
                acc[i][j] = __builtin_amdgcn_mfma_f32_16x16x32_bf16(af[i], bfr[j], acc[i][j], 0, 0, 0);
    }

    // ---- VFOLD: store this tile transposed, straight from acc ----
    if constexpr (VFOLD) {
        if (n0 >= nsplit) {
            unsigned short* Vp = VtOut + (long long)bz * sVt;
#pragma unroll
            for (int i = 0; i < 4; i++) {
                const int t = m0 + wr * 64 + i * 16 + quad * 4;
#pragma unroll
                for (int j = 0; j < 4; j++) {
                    const int d = (n0 - nsplit) + wc * 64 + j * 16 + lrow;
                    union { unsigned short u[4]; uint2 p; } o;
#pragma unroll
                    for (int r = 0; r < 4; r++) o.u[r] = f2bf(acc[i][j][r] * scale);
                    *(uint2*)(Vp + (long long)d * ldvt + t) = o.p;
                }
            }
            return;
        }
    }

    __syncthreads();   // all waves done before LDS is reused for repack

    // ---- epilogue: per-wave LDS repack (16 rows x 144 B stride, 2288 B/wave) ----
    char* eb = (char*)LDS + w * 2288;
    const int erow = l >> 2, ep = l & 3;

    if constexpr (sizeof(OutT) == 2) {
#pragma unroll
        for (int i = 0; i < 4; i++) {
#pragma unroll
            for (int j = 0; j < 4; j++)
#pragma unroll
                for (int r = 0; r < 4; r++)
                    *(unsigned short*)(eb + (quad * 4 + r) * 144 + (j * 16 + lrow) * 2) =
                        f2bf(acc[i][j][r] * scale);
            const long long gm = m0 + wr * 64 + i * 16 + erow;
#pragma unroll
            for (int c = 0; c < 2; c++) {
                u32x4 d = *(u32x4*)(eb + erow * 144 + ep * 32 + c * 16);
                *(u32x4*)((unsigned short*)C + gm * ldc + (n0 + wc * 64 + ep * 16 + c * 8)) = d;
            }
        }
    } else {
#pragma unroll
        for (int i = 0; i < 4; i++) {
            const long long gm = m0 + wr * 64 + i * 16 + erow;
#pragma unroll
            for (int jc = 0; jc < 2; jc++) {
#pragma unroll
                for (int jj = 0; jj < 2; jj++)
#pragma unroll
                    for (int r = 0; r < 4; r++)
                        *(float*)(eb + (quad * 4 + r) * 144 + (jj * 16 + lrow) * 4) =
                            acc[i][2 * jc + jj][r] * scale;
#pragma unroll
                for (int c = 0; c < 2; c++) {
                    f32x4 d = *(f32x4*)(eb + erow * 144 + ep * 32 + c * 16);
                    *(f32x4*)((float*)C + gm * ldc + (n0 + wc * 64 + jc * 32 + ep * 8 + c * 4)) = d;
                }
            }
        }
    }
}

// ---------- fp32 -> bf16 cast (vectorized) ----------
__global__ __launch_bounds__(256) void cast_f32_bf16(
    const float4* __restrict__ in, unsigned short* __restrict__ out, int n4)
{
    int i = blockIdx.x * 256 + threadIdx.x;
    if (i >= n4) return;
    float4 v = in[i];
    union { unsigned short u[4]; uint2 p; } o;
    o.u[0] = f2bf(v.x); o.u[1] = f2bf(v.y); o.u[2] = f2bf(v.z); o.u[3] = f2bf(v.w);
    *(uint2*)(out + (long long)i * 4) = o.p;
}

// ---------- fused W_{q,k,v} (1024x1024 fp32) -> concatenated W^T (3072 x 1024 bf16) ----------
__global__ __launch_bounds__(256) void transpose_cast_w3(
    const float* __restrict__ W0, const float* __restrict__ W1,
    const float* __restrict__ W2, unsigned short* __restrict__ out, int n)
{
    const float* in = (blockIdx.z == 0) ? W0 : (blockIdx.z == 1) ? W1 : W2;
    out += (long long)blockIdx.z * n * n;
    __shared__ float tile[32][33];
    const int tx = threadIdx.x, ty = threadIdx.y;
    const int c0 = blockIdx.x * 32, r0 = blockIdx.y * 32;
#pragma unroll
    for (int i = 0; i < 4; i++)
        tile[ty + i * 8][tx] = in[(long long)(r0 + ty + i * 8) * n + c0 + tx];
    __syncthreads();
#pragma unroll
    for (int i = 0; i < 4; i++)
        out[(long long)(c0 + ty + i * 8) * n + r0 + tx] = f2bf(tile[tx][ty + i * 8]);
}

// ---------- causal softmax: S (bf16, B*T rows of T) -> P (bf16), vectorized ----------
__global__ __launch_bounds__(256) void causal_softmax_bf16(
    const unsigned short* __restrict__ S, unsigned short* __restrict__ P, int T)
{
    const int row = blockIdx.x;            // 0 .. B*T-1
    const int t   = row & (T - 1);
    const int L   = t + 1;
    const unsigned short* s = S + (long long)row * T;
    unsigned short* p = P + (long long)row * T;
    const int tid  = threadIdx.x;
    const int base = tid * 8;

    uint4 raw = *(const uint4*)(s + base);
    unsigned rr[4] = {raw.x, raw.y, raw.z, raw.w};
    float v[8];
#pragma unroll
    for (int k = 0; k < 4; k++) {
        union { unsigned u; float f; } a, b;
        a.u = (rr[k] & 0xFFFFu) << 16;
        b.u = rr[k] & 0xFFFF0000u;
        v[2 * k] = a.f; v[2 * k + 1] = b.f;
    }
    float mx = -3.0e38f;
#pragma unroll
    for (int k = 0; k < 8; k++) {
        if (base + k >= L) v[k] = -3.0e38f;
        mx = fmaxf(mx, v[k]);
    }
#pragma unroll
    for (int off = 32; off; off >>= 1) mx = fmaxf(mx, __shfl_xor(mx, off));
    __shared__ float red[4], red2[4];
    const int wid = tid >> 6, lid = tid & 63;
    if (lid == 0) red[wid] = mx;
    __syncthreads();
    mx = fmaxf(fmaxf(red[0], red[1]), fmaxf(red[2], red[3]));

    float sum = 0.f;
#pragma unroll
    for (int k = 0; k < 8; k++) { v[k] = __expf(v[k] - mx); sum += v[k]; }
#pragma unroll
    for (int off = 32; off; off >>= 1) sum += __shfl_xor(sum, off);
    if (lid == 0) red2[wid] = sum;
    __syncthreads();
    sum = red2[0] + red2[1] + red2[2] + red2[3];
    const float inv = 1.0f / sum;

    union { unsigned short u[8]; uint4 q; } o;
#pragma unroll
    for (int k = 0; k < 8; k++) o.u[k] = f2bf(v[k] * inv);
    *(uint4*)(p + base) = o.q;
}

// ---------- launch ----------
extern "C" void kernel_launch(void* const* d_in, const int* in_sizes, int n_in,
                              void* d_out, int out_size, void* d_ws, size_t ws_size,
                              hipStream_t stream)
{
    const int B = 4, T = 2048, C = 1024, D = 1024;
    const float* x  = (const float*)d_in[0];
    const float* Wq = (const float*)d_in[1];
    const float* Wk = (const float*)d_in[2];
    const float* Wv = (const float*)d_in[3];
    float* out = (float*)d_out;
    char* ws = (char*)d_ws;

    const size_t MB = 1ull << 20;
    // layout (peak 102 MB):
    //  0..16   Xbf          [dead after QKV gemm]
    // 16..22   WqkvT        [dead after QKV gemm]
    // 22..54   QK  (4 x 2048 x 2048 bf16: Q cols 0..1023, K cols 1024..2047)
    // 54..70   Vt  (4 x 1024 x 2048 bf16, written by QKV epilogue VFOLD)
    // 70..102  Sbf (4 x 2048 x 2048 bf16)
    //  0..32   P   (4 x 2048 x 2048 bf16) [overlays dead Xbf/WqkvT/QK-head]
    unsigned short* Xbf   = (unsigned short*)(ws + 0);
    unsigned short* WqkvT = (unsigned short*)(ws + 16 * MB);
    unsigned short* QK    = (unsigned short*)(ws + 22 * MB);
    unsigned short* Vt    = (unsigned short*)(ws + 54 * MB);
    unsigned short* Sbf   = (unsigned short*)(ws + 70 * MB);
    unsigned short* P     = (unsigned short*)(ws + 0);

    const long long sX  = (long long)T * C;        // 2048*1024
    const long long sQK = (long long)T * 2 * D;    // 2048*2048
    const long long sVt = (long long)D * T;        // 1024*2048
    const long long sS  = (long long)T * T;        // 2048*2048
    const long long sO  = (long long)T * D;        // 2048*1024

    // 1) x -> bf16
    {
        int n4 = B * T * C / 4;
        cast_f32_bf16<<<dim3((n4 + 255) / 256), dim3(256), 0, stream>>>(
            (const float4*)x, Xbf, n4);
    }
    // 2) fused W^T cast
    {
        dim3 g(32, 32, 3), b(32, 8);
        transpose_cast_w3<<<g, b, 0, stream>>>(Wq, Wk, Wv, WqkvT, 1024);
    }
    // 3) fused QKV GEMM: Q,K -> QK (ldc 2048); V third -> Vt transposed (VFOLD)
    //    XSWZ: XCD-chunked bn for L2-resident B panels.
    {
        dim3 g(3072 / 128, 2048 / 128, 4), b(256);
        gemm_bt<unsigned short, false, false, true, true><<<g, b, 0, stream>>>(
            Xbf, WqkvT, QK, Vt, 2048, 3072, 1024, 1024, 1024, 2048,
            /*ldvt*/ T, /*nsplit*/ 2048, sX, 0, sQK, sVt, 1.0f);
    }
    // 4) S = Q K^T / 32 -> bf16, TRIANGULAR-PACKED causal grid (136 blocks/z,
    //    bn<=bm only), XCD-chunked so same-bm blocks share an XCD's L2.
    {
        dim3 g(136, 1, 4), b(256);
        gemm_bt<unsigned short, false, false, false, false, true><<<g, b, 0, stream>>>(
            QK, QK + D, Sbf, nullptr, 2048, 2048, 1024, 2 * D, 2 * D, 2048,
            0, 0, sQK, sQK, sS, 0, 0.03125f);
    }
    // 5) causal softmax (bf16 -> bf16)
    {
        causal_softmax_bf16<<<dim3(B * T), dim3(256), 0, stream>>>(Sbf, P, T);
    }
    // 6) O = P V (K clamped causally, heavy row-blocks dispatched first), fp32 out
    {
        dim3 g(1024 / 128, 2048 / 128, 4), b(256);
        gemm_bt<float, false, true, false><<<g, b, 0, stream>>>(
            P, Vt, out, nullptr, 2048, 1024, 2048, 2048, 2048, 1024,
            0, 0, sS, sVt, sO, 0, 1.0f);
    }
    (void)in_sizes; (void)n_in; (void)out_size; (void)ws_size;
}

// Round 6
// 236.788 us; speedup vs baseline: 1.0830x; 1.0336x over previous
//
#include <hip/hip_runtime.h>
#include <hip/hip_bf16.h>
#include <stdint.h>
#include <math.h>

// ---------- types ----------
typedef __bf16 bf16x8 __attribute__((ext_vector_type(8)));
typedef float  f32x4  __attribute__((ext_vector_type(4)));
typedef unsigned int u32x4 __attribute__((ext_vector_type(4)));

__device__ __forceinline__ unsigned short f2bf(float x) {
    union { float f; unsigned u; } v; v.f = x;
    unsigned r = v.u + 0x7fffu + ((v.u >> 16) & 1u);   // RNE
    return (unsigned short)(r >> 16);
}

__device__ __forceinline__ float bf2f(unsigned short b) {
    union { unsigned u; float f; } v; v.u = ((unsigned)b) << 16; return v.f;
}

__device__ __forceinline__ void async16(const void* g, void* l) {
    __builtin_amdgcn_global_load_lds(
        (const __attribute__((address_space(1))) void*)g,
        (__attribute__((address_space(3))) void*)l,
        16, 0, 0);
}

// ---------- bf16 B^T GEMM, 128x128 tile, BK=32, 4 waves, DOUBLE-BUFFERED ----------
// A: M x K (row-major bf16 bits, lda), Bt: N x K (row-major, ldb)
// C[m][n] = scale * sum_k A[m][k] * Bt[n][k]
// VFOLD: for n0 >= nsplit the 128x128 output tile is stored TRANSPOSED to VtOut.
// KLIMIT: K clamped causally per row-block (Keff = (bm+1)*128).
//
// Z-PURE XCD SWIZZLE (ZMODE): with gridDim.x % 8 == 0 the HW round-robin gives
// XCD = blockIdx.x & 7 for every z. Each XCD is assigned ONE batch slice
// (bz = xcd>>1; 2 XCDs per batch) and a bijective tile unpack from
// (xcd&1, blockIdx.x>>3, blockIdx.z), shrinking the per-XCD L2 working set
// from ~25 MB (z-mixed) to ~6-7 MB.
//   ZMODE=1 QKV: gx=384,gz=4; tile=(x&1)*192+q*4+z -> bn=tile/16, bm=tile%16
//   ZMODE=2 S:   gx=136,gz=4; t=(x&1)*68+q*4+z -> triangular (bm,bn), bn<=bm
//   ZMODE=3 PV:  gx=128,gz=4; tile=(x&1)*64+q*4+z -> bn=tile>>4, bm=15-(tile&15)
template <typename OutT, bool KLIMIT, bool VFOLD, int ZMODE>
__global__ __launch_bounds__(256, 4) void gemm_bt(
    const unsigned short* __restrict__ A,
    const unsigned short* __restrict__ Bt,
    OutT* __restrict__ C,
    unsigned short* __restrict__ VtOut,
    int M, int N, int K, int lda, int ldb, int ldc,
    int ldvt, int nsplit,
    long long sA, long long sB, long long sC, long long sVt, float scale)
{
    int bn, bm, bz;
    if constexpr (ZMODE == 1) {            // QKV: 24 bn x 16 bm per z
        const int o = blockIdx.x, x = o & 7, q = o >> 3;
        bz = x >> 1;
        const int tile = (x & 1) * 192 + q * 4 + blockIdx.z;
        bn = tile / 16; bm = tile % 16;    // XCD covers 12 contig bn x all bm
    } else if constexpr (ZMODE == 2) {     // S: packed causal triangle (136/z)
        const int o = blockIdx.x, x = o & 7, q = o >> 3;
        bz = x >> 1;
        const int t = (x & 1) * 68 + q * 4 + blockIdx.z;
        int r = (int)((sqrtf(8.f * (float)t + 1.f) - 1.f) * 0.5f);
        while ((r + 1) * (r + 2) / 2 <= t) r++;
        while (r * (r + 1) / 2 > t) r--;
        bm = r; bn = t - r * (r + 1) / 2;  // bn <= bm
    } else if constexpr (ZMODE == 3) {     // PV: 8 bn x 16 bm per z, heavy-first
        const int o = blockIdx.x, x = o & 7, q = o >> 3;
        bz = x >> 1;
        const int tile = (x & 1) * 64 + q * 4 + blockIdx.z;
        bn = tile >> 4; bm = 15 - (tile & 15);
    } else {
        bn = blockIdx.x;
        bm = KLIMIT ? (gridDim.y - 1 - blockIdx.y) : blockIdx.y;
        bz = blockIdx.z;
    }

    A  += (long long)bz * sA;
    Bt += (long long)bz * sB;
    C  += (long long)bz * sC;

    const int m0 = bm * 128, n0 = bn * 128;
    const int Keff = KLIMIT ? min(K, (bm + 1) * 128) : K;

    // [buf][A:128x32 | B:128x32], 16 KB per buffer
    __shared__ __align__(16) unsigned short LDS[2 * 2 * 128 * 32];

    const int tid  = threadIdx.x;
    const int w    = tid >> 6, l = tid & 63;
    const int wr   = w >> 1,  wc = w & 1;
    const int lrow = l & 15,  quad = l >> 4;

    f32x4 acc[4][4] = {};

    // staging: lane l of chunk c covers row 16c + (l>>2); physical k-slot l&3
    // holds logical chunk (l&3)^((l>>3)&3) (row-pair swizzle).
    const int rA0  = 32 * w + (l >> 2);
    const int cOff = (((l & 3) ^ ((l >> 3) & 3))) * 8;
    const unsigned short* aG0 = A  + (long long)(m0 + rA0)      * lda + cOff;
    const unsigned short* aG1 = A  + (long long)(m0 + rA0 + 16) * lda + cOff;
    const unsigned short* bG0 = Bt + (long long)(n0 + rA0)      * ldb + cOff;
    const unsigned short* bG1 = Bt + (long long)(n0 + rA0 + 16) * ldb + cOff;
    unsigned short* aL = &LDS[(2 * w) * 512 + l * 8];           // A region of buf0
    unsigned short* bL = aL + 4096;                             // B region of buf0

    const int sl = (lrow >> 1) & 3;   // un-swizzle for fragment reads

    // prologue: stage tile 0 into buf 0
    async16(aG0, aL);
    async16(aG1, aL + 512);
    async16(bG0, bL);
    async16(bG1, bL + 512);

    for (int k0 = 0; k0 < Keff; k0 += 32) {
        const int cur = ((k0 >> 5) & 1) * 8192;   // element offset of current buf
        __syncthreads();                          // tile k0 ready in cur

        if (k0 + 32 < Keff) {                     // prefetch tile k0+32 into other buf
            const int nxt = cur ^ 8192;
            async16(aG0 + k0 + 32, aL + nxt);
            async16(aG1 + k0 + 32, aL + nxt + 512);
            async16(bG0 + k0 + 32, bL + nxt);
            async16(bG1 + k0 + 32, bL + nxt + 512);
        }

        const unsigned short* As = &LDS[cur];
        const unsigned short* Bs = &LDS[cur + 4096];
        bf16x8 af[4], bfr[4];
#pragma unroll
        for (int i = 0; i < 4; i++) {
            af[i]  = *(const bf16x8*)&As[(wr * 64 + i * 16 + lrow) * 32 + (quad ^ sl) * 8];
            bfr[i] = *(const bf16x8*)&Bs[(wc * 64 + i * 16 + lrow) * 32 + (quad ^ sl) * 8];
        }
#pragma unroll
        for (int i = 0; i < 4; i++)
#pragma unroll
            for (int j = 0; j < 4; j++)
                acc[i][j] = __builtin_amdgcn_mfma_f32_16x16x32_bf16(af[i], bfr[j], acc[i][j], 0, 0, 0);
    }

    // ---- VFOLD: store this tile transposed, straight from acc ----
    if constexpr (VFOLD) {
        if (n0 >= nsplit) {
            unsigned short* Vp = VtOut + (long long)bz * sVt;
#pragma unroll
            for (int i = 0; i < 4; i++) {
                const int t = m0 + wr * 64 + i * 16 + quad * 4;
#pragma unroll
                for (int j = 0; j < 4; j++) {
                    const int d = (n0 - nsplit) + wc * 64 + j * 16 + lrow;
                    union { unsigned short u[4]; uint2 p; } o;
#pragma unroll
                    for (int r = 0; r < 4; r++) o.u[r] = f2bf(acc[i][j][r] * scale);
                    *(uint2*)(Vp + (long long)d * ldvt + t) = o.p;
                }
            }
            return;
        }
    }

    __syncthreads();   // all waves done before LDS is reused for repack

    // ---- epilogue: per-wave LDS repack (16 rows x 144 B stride, 2288 B/wave) ----
    char* eb = (char*)LDS + w * 2288;
    const int erow = l >> 2, ep = l & 3;

    if constexpr (sizeof(OutT) == 2) {
#pragma unroll
        for (int i = 0; i < 4; i++) {
#pragma unroll
            for (int j = 0; j < 4; j++)
#pragma unroll
                for (int r = 0; r < 4; r++)
                    *(unsigned short*)(eb + (quad * 4 + r) * 144 + (j * 16 + lrow) * 2) =
                        f2bf(acc[i][j][r] * scale);
            const long long gm = m0 + wr * 64 + i * 16 + erow;
#pragma unroll
            for (int c = 0; c < 2; c++) {
                u32x4 d = *(u32x4*)(eb + erow * 144 + ep * 32 + c * 16);
                *(u32x4*)((unsigned short*)C + gm * ldc + (n0 + wc * 64 + ep * 16 + c * 8)) = d;
            }
        }
    } else {
#pragma unroll
        for (int i = 0; i < 4; i++) {
            const long long gm = m0 + wr * 64 + i * 16 + erow;
#pragma unroll
            for (int jc = 0; jc < 2; jc++) {
#pragma unroll
                for (int jj = 0; jj < 2; jj++)
#pragma unroll
                    for (int r = 0; r < 4; r++)
                        *(float*)(eb + (quad * 4 + r) * 144 + (jj * 16 + lrow) * 4) =
                            acc[i][2 * jc + jj][r] * scale;
#pragma unroll
                for (int c = 0; c < 2; c++) {
                    f32x4 d = *(f32x4*)(eb + erow * 144 + ep * 32 + c * 16);
                    *(f32x4*)((float*)C + gm * ldc + (n0 + wc * 64 + jc * 32 + ep * 8 + c * 4)) = d;
                }
            }
        }
    }
}

// ---------- fp32 -> bf16 cast (vectorized) ----------
__global__ __launch_bounds__(256) void cast_f32_bf16(
    const float4* __restrict__ in, unsigned short* __restrict__ out, int n4)
{
    int i = blockIdx.x * 256 + threadIdx.x;
    if (i >= n4) return;
    float4 v = in[i];
    union { unsigned short u[4]; uint2 p; } o;
    o.u[0] = f2bf(v.x); o.u[1] = f2bf(v.y); o.u[2] = f2bf(v.z); o.u[3] = f2bf(v.w);
    *(uint2*)(out + (long long)i * 4) = o.p;
}

// ---------- fused W_{q,k,v} (1024x1024 fp32) -> concatenated W^T (3072 x 1024 bf16) ----------
__global__ __launch_bounds__(256) void transpose_cast_w3(
    const float* __restrict__ W0, const float* __restrict__ W1,
    const float* __restrict__ W2, unsigned short* __restrict__ out, int n)
{
    const float* in = (blockIdx.z == 0) ? W0 : (blockIdx.z == 1) ? W1 : W2;
    out += (long long)blockIdx.z * n * n;
    __shared__ float tile[32][33];
    const int tx = threadIdx.x, ty = threadIdx.y;
    const int c0 = blockIdx.x * 32, r0 = blockIdx.y * 32;
#pragma unroll
    for (int i = 0; i < 4; i++)
        tile[ty + i * 8][tx] = in[(long long)(r0 + ty + i * 8) * n + c0 + tx];
    __syncthreads();
#pragma unroll
    for (int i = 0; i < 4; i++)
        out[(long long)(c0 + ty + i * 8) * n + r0 + tx] = f2bf(tile[tx][ty + i * 8]);
}

// ---------- causal softmax: S (bf16, B*T rows of T) -> P (bf16), vectorized ----------
__global__ __launch_bounds__(256) void causal_softmax_bf16(
    const unsigned short* __restrict__ S, unsigned short* __restrict__ P, int T)
{
    const int row = blockIdx.x;            // 0 .. B*T-1
    const int t   = row & (T - 1);
    const int L   = t + 1;
    const unsigned short* s = S + (long long)row * T;
    unsigned short* p = P + (long long)row * T;
    const int tid  = threadIdx.x;
    const int base = tid * 8;

    uint4 raw = *(const uint4*)(s + base);
    unsigned rr[4] = {raw.x, raw.y, raw.z, raw.w};
    float v[8];
#pragma unroll
    for (int k = 0; k < 4; k++) {
        union { unsigned u; float f; } a, b;
        a.u = (rr[k] & 0xFFFFu) << 16;
        b.u = rr[k] & 0xFFFF0000u;
        v[2 * k] = a.f; v[2 * k + 1] = b.f;
    }
    float mx = -3.0e38f;
#pragma unroll
    for (int k = 0; k < 8; k++) {
        if (base + k >= L) v[k] = -3.0e38f;
        mx = fmaxf(mx, v[k]);
    }
#pragma unroll
    for (int off = 32; off; off >>= 1) mx = fmaxf(mx, __shfl_xor(mx, off));
    __shared__ float red[4], red2[4];
    const int wid = tid >> 6, lid = tid & 63;
    if (lid == 0) red[wid] = mx;
    __syncthreads();
    mx = fmaxf(fmaxf(red[0], red[1]), fmaxf(red[2], red[3]));

    float sum = 0.f;
#pragma unroll
    for (int k = 0; k < 8; k++) { v[k] = __expf(v[k] - mx); sum += v[k]; }
#pragma unroll
    for (int off = 32; off; off >>= 1) sum += __shfl_xor(sum, off);
    if (lid == 0) red2[wid] = sum;
    __syncthreads();
    sum = red2[0] + red2[1] + red2[2] + red2[3];
    const float inv = 1.0f / sum;

    union { unsigned short u[8]; uint4 q; } o;
#pragma unroll
    for (int k = 0; k < 8; k++) o.u[k] = f2bf(v[k] * inv);
    *(uint4*)(p + base) = o.q;
}

// ---------- launch ----------
extern "C" void kernel_launch(void* const* d_in, const int* in_sizes, int n_in,
                              void* d_out, int out_size, void* d_ws, size_t ws_size,
                              hipStream_t stream)
{
    const int B = 4, T = 2048, C = 1024, D = 1024;
    const float* x  = (const float*)d_in[0];
    const float* Wq = (const float*)d_in[1];
    const float* Wk = (const float*)d_in[2];
    const float* Wv = (const float*)d_in[3];
    float* out = (float*)d_out;
    char* ws = (char*)d_ws;

    const size_t MB = 1ull << 20;
    // layout (peak 102 MB):
    //  0..16   Xbf          [dead after QKV gemm]
    // 16..22   WqkvT        [dead after QKV gemm]
    // 22..54   QK  (4 x 2048 x 2048 bf16: Q cols 0..1023, K cols 1024..2047)
    // 54..70   Vt  (4 x 1024 x 2048 bf16, written by QKV epilogue VFOLD)
    // 70..102  Sbf (4 x 2048 x 2048 bf16)
    //  0..32   P   (4 x 2048 x 2048 bf16) [overlays dead Xbf/WqkvT/QK-head]
    unsigned short* Xbf   = (unsigned short*)(ws + 0);
    unsigned short* WqkvT = (unsigned short*)(ws + 16 * MB);
    unsigned short* QK    = (unsigned short*)(ws + 22 * MB);
    unsigned short* Vt    = (unsigned short*)(ws + 54 * MB);
    unsigned short* Sbf   = (unsigned short*)(ws + 70 * MB);
    unsigned short* P     = (unsigned short*)(ws + 0);

    const long long sX  = (long long)T * C;        // 2048*1024
    const long long sQK = (long long)T * 2 * D;    // 2048*2048
    const long long sVt = (long long)D * T;        // 1024*2048
    const long long sS  = (long long)T * T;        // 2048*2048
    const long long sO  = (long long)T * D;        // 2048*1024

    // 1) x -> bf16
    {
        int n4 = B * T * C / 4;
        cast_f32_bf16<<<dim3((n4 + 255) / 256), dim3(256), 0, stream>>>(
            (const float4*)x, Xbf, n4);
    }
    // 2) fused W^T cast
    {
        dim3 g(32, 32, 3), b(32, 8);
        transpose_cast_w3<<<g, b, 0, stream>>>(Wq, Wk, Wv, WqkvT, 1024);
    }
    // 3) fused QKV GEMM: Q,K -> QK (ldc 2048); V third -> Vt transposed (VFOLD)
    //    ZMODE=1: z-pure XCD swizzle (each XCD serves one batch slice).
    {
        dim3 g(384, 1, 4), b(256);
        gemm_bt<unsigned short, false, true, 1><<<g, b, 0, stream>>>(
            Xbf, WqkvT, QK, Vt, 2048, 3072, 1024, 1024, 1024, 2048,
            /*ldvt*/ T, /*nsplit*/ 2048, sX, 0, sQK, sVt, 1.0f);
    }
    // 4) S = Q K^T / 32 -> bf16, triangular-packed causal grid, z-pure XCD
    {
        dim3 g(136, 1, 4), b(256);
        gemm_bt<unsigned short, false, false, 2><<<g, b, 0, stream>>>(
            QK, QK + D, Sbf, nullptr, 2048, 2048, 1024, 2 * D, 2 * D, 2048,
            0, 0, sQK, sQK, sS, 0, 0.03125f);
    }
    // 5) causal softmax (bf16 -> bf16)
    {
        causal_softmax_bf16<<<dim3(B * T), dim3(256), 0, stream>>>(Sbf, P, T);
    }
    // 6) O = P V (K clamped causally, heavy-first within XCD), z-pure XCD
    {
        dim3 g(128, 1, 4), b(256);
        gemm_bt<float, true, false, 3><<<g, b, 0, stream>>>(
            P, Vt, out, nullptr, 2048, 1024, 2048, 2048, 2048, 1024,
            0, 0, sS, sVt, sO, 0, 1.0f);
    }
    (void)in_sizes; (void)n_in; (void)out_size; (void)ws_size;
}

// Round 7
// 232.968 us; speedup vs baseline: 1.1008x; 1.0164x over previous
//
#include <hip/hip_runtime.h>
#include <hip/hip_bf16.h>
#include <stdint.h>
#include <math.h>

// ---------- types ----------
typedef __bf16 bf16x8 __attribute__((ext_vector_type(8)));
typedef float  f32x4  __attribute__((ext_vector_type(4)));
typedef unsigned int u32x4 __attribute__((ext_vector_type(4)));

__device__ __forceinline__ unsigned short f2bf(float x) {
    union { float f; unsigned u; } v; v.f = x;
    unsigned r = v.u + 0x7fffu + ((v.u >> 16) & 1u);   // RNE
    return (unsigned short)(r >> 16);
}

__device__ __forceinline__ float bf2f(unsigned short b) {
    union { unsigned u; float f; } v; v.u = ((unsigned)b) << 16; return v.f;
}

__device__ __forceinline__ void async16(const void* g, void* l) {
    __builtin_amdgcn_global_load_lds(
        (const __attribute__((address_space(1))) void*)g,
        (__attribute__((address_space(3))) void*)l,
        16, 0, 0);
}

// ---------- bf16 B^T GEMM, 128x128 tile, BK=32, 4 waves ----------
// TRIPLE-BUFFERED K-loop with counted vmcnt (T4): stage tile t+2 each iter;
// at iter t wait vmcnt(4) only (stage t+1's 4 loads stay in flight across
// the barrier). Raw s_barrier + "memory"-clobber asm on both sides replaces
// __syncthreads' vmcnt(0) drain — the 72% stall of the 2-phase structure.
// WAR-safe: buf[(t+2)%3] was last read at iter t-1, and those ds_reads
// complete before each wave's pre-barrier lgkmcnt.
//
// A: M x K (row-major bf16 bits, lda), Bt: N x K (row-major, ldb)
// C[m][n] = scale * sum_k A[m][k] * Bt[n][k]
// VFOLD: for n0 >= nsplit the tile is stored TRANSPOSED to VtOut.
// KLIMIT: K clamped causally per row-block (Keff = (bm+1)*128).
// ZMODE (z-pure XCD swizzle, gridDim.x%8==0 => XCD = blockIdx.x&7):
//   1 QKV: gx=384,gz=4; tile=(x&1)*192+q*4+z -> bn=tile/16, bm=tile%16
//   2 S:   gx=136,gz=4; t=(x&1)*68+q*4+z -> triangular (bm,bn), bn<=bm
//   3 PV:  gx=128,gz=4; tile=(x&1)*64+q*4+z -> bn=tile>>4, bm=15-(tile&15)
template <typename OutT, bool KLIMIT, bool VFOLD, int ZMODE>
__global__ __launch_bounds__(256, 3) void gemm_bt(
    const unsigned short* __restrict__ A,
    const unsigned short* __restrict__ Bt,
    OutT* __restrict__ C,
    unsigned short* __restrict__ VtOut,
    int M, int N, int K, int lda, int ldb, int ldc,
    int ldvt, int nsplit,
    long long sA, long long sB, long long sC, long long sVt, float scale)
{
    int bn, bm, bz;
    if constexpr (ZMODE == 1) {            // QKV: 24 bn x 16 bm per z
        const int o = blockIdx.x, x = o & 7, q = o >> 3;
        bz = x >> 1;
        const int tile = (x & 1) * 192 + q * 4 + blockIdx.z;
        bn = tile / 16; bm = tile % 16;
    } else if constexpr (ZMODE == 2) {     // S: packed causal triangle (136/z)
        const int o = blockIdx.x, x = o & 7, q = o >> 3;
        bz = x >> 1;
        const int t = (x & 1) * 68 + q * 4 + blockIdx.z;
        int r = (int)((sqrtf(8.f * (float)t + 1.f) - 1.f) * 0.5f);
        while ((r + 1) * (r + 2) / 2 <= t) r++;
        while (r * (r + 1) / 2 > t) r--;
        bm = r; bn = t - r * (r + 1) / 2;  // bn <= bm
    } else if constexpr (ZMODE == 3) {     // PV: 8 bn x 16 bm per z, heavy-first
        const int o = blockIdx.x, x = o & 7, q = o >> 3;
        bz = x >> 1;
        const int tile = (x & 1) * 64 + q * 4 + blockIdx.z;
        bn = tile >> 4; bm = 15 - (tile & 15);
    } else {
        bn = blockIdx.x;
        bm = KLIMIT ? (gridDim.y - 1 - blockIdx.y) : blockIdx.y;
        bz = blockIdx.z;
    }

    A  += (long long)bz * sA;
    Bt += (long long)bz * sB;
    C  += (long long)bz * sC;

    const int m0 = bm * 128, n0 = bn * 128;
    const int Keff = KLIMIT ? min(K, (bm + 1) * 128) : K;
    const int nsteps = Keff >> 5;

    // 3 bufs x [A:128x32 | B:128x32] = 48 KB
    __shared__ __align__(16) unsigned short LDS[3 * 8192];

    const int tid  = threadIdx.x;
    const int w    = tid >> 6, l = tid & 63;
    const int wr   = w >> 1,  wc = w & 1;
    const int lrow = l & 15,  quad = l >> 4;

    f32x4 acc[4][4] = {};

    // staging: lane l of chunk c covers row 16c + (l>>2); physical k-slot l&3
    // holds logical chunk (l&3)^((l>>3)&3) (row-pair swizzle).
    const int rA0  = 32 * w + (l >> 2);
    const int cOff = (((l & 3) ^ ((l >> 3) & 3))) * 8;
    const unsigned short* aG0 = A  + (long long)(m0 + rA0)      * lda + cOff;
    const unsigned short* aG1 = A  + (long long)(m0 + rA0 + 16) * lda + cOff;
    const unsigned short* bG0 = Bt + (long long)(n0 + rA0)      * ldb + cOff;
    const unsigned short* bG1 = Bt + (long long)(n0 + rA0 + 16) * ldb + cOff;
    unsigned short* aL = &LDS[(2 * w) * 512 + l * 8];           // A region of buf0
    unsigned short* bL = aL + 4096;                             // B region of buf0

    const int sl = (lrow >> 1) & 3;   // un-swizzle for fragment reads

    // stage K-tile s into buf s%3 (4 x 16B loads per thread)
    auto STG = [&](int s) {
        const int off = (s % 3) * 8192;
        const int kk  = s * 32;
        async16(aG0 + kk, aL + off);
        async16(aG1 + kk, aL + off + 512);
        async16(bG0 + kk, bL + off);
        async16(bG1 + kk, bL + off + 512);
    };

    STG(0);
    if (nsteps > 1) STG(1);

    for (int t = 0; t < nsteps; ++t) {
        // wait for stage t only (stage t+1's 4 loads stay in flight)
        if (t + 1 < nsteps) asm volatile("s_waitcnt vmcnt(4)" ::: "memory");
        else                asm volatile("s_waitcnt vmcnt(0)" ::: "memory");
        __builtin_amdgcn_s_barrier();
        asm volatile("" ::: "memory");            // no LDS-read hoist above barrier

        if (t + 2 < nsteps) STG(t + 2);           // overwrites buf last read at t-1

        const unsigned short* As = &LDS[(t % 3) * 8192];
        const unsigned short* Bs = As + 4096;
        bf16x8 af[4], bfr[4];
#pragma unroll
        for (int i = 0; i < 4; i++) {
            af[i]  = *(const bf16x8*)&As[(wr * 64 + i * 16 + lrow) * 32 + (quad ^ sl) * 8];
            bfr[i] = *(const bf16x8*)&Bs[(wc * 64 + i * 16 + lrow) * 32 + (quad ^ sl) * 8];
        }
#pragma unroll
        for (int i = 0; i < 4; i++)
#pragma unroll
            for (int j = 0; j < 4; j++)
                acc[i][j] = __builtin_amdgcn_mfma_f32_16x16x32_bf16(af[i], bfr[j], acc[i][j], 0, 0, 0);
    }

    // ---- VFOLD: store this tile transposed, straight from acc ----
    if constexpr (VFOLD) {
        if (n0 >= nsplit) {
            unsigned short* Vp = VtOut + (long long)bz * sVt;
#pragma unroll
            for (int i = 0; i < 4; i++) {
                const int t = m0 + wr * 64 + i * 16 + quad * 4;
#pragma unroll
                for (int j = 0; j < 4; j++) {
                    const int d = (n0 - nsplit) + wc * 64 + j * 16 + lrow;
                    union { unsigned short u[4]; uint2 p; } o;
#pragma unroll
                    for (int r = 0; r < 4; r++) o.u[r] = f2bf(acc[i][j][r] * scale);
                    *(uint2*)(Vp + (long long)d * ldvt + t) = o.p;
                }
            }
            return;
        }
    }

    __syncthreads();   // all waves done before LDS is reused for repack

    // ---- epilogue: per-wave LDS repack (16 rows x 144 B stride, 2288 B/wave) ----
    char* eb = (char*)LDS + w * 2288;
    const int erow = l >> 2, ep = l & 3;

    if constexpr (sizeof(OutT) == 2) {
#pragma unroll
        for (int i = 0; i < 4; i++) {
#pragma unroll
            for (int j = 0; j < 4; j++)
#pragma unroll
                for (int r = 0; r < 4; r++)
                    *(unsigned short*)(eb + (quad * 4 + r) * 144 + (j * 16 + lrow) * 2) =
                        f2bf(acc[i][j][r] * scale);
            const long long gm = m0 + wr * 64 + i * 16 + erow;
#pragma unroll
            for (int c = 0; c < 2; c++) {
                u32x4 d = *(u32x4*)(eb + erow * 144 + ep * 32 + c * 16);
                *(u32x4*)((unsigned short*)C + gm * ldc + (n0 + wc * 64 + ep * 16 + c * 8)) = d;
            }
        }
    } else {
#pragma unroll
        for (int i = 0; i < 4; i++) {
            const long long gm = m0 + wr * 64 + i * 16 + erow;
#pragma unroll
            for (int jc = 0; jc < 2; jc++) {
#pragma unroll
                for (int jj = 0; jj < 2; jj++)
#pragma unroll
                    for (int r = 0; r < 4; r++)
                        *(float*)(eb + (quad * 4 + r) * 144 + (jj * 16 + lrow) * 4) =
                            acc[i][2 * jc + jj][r] * scale;
#pragma unroll
                for (int c = 0; c < 2; c++) {
                    f32x4 d = *(f32x4*)(eb + erow * 144 + ep * 32 + c * 16);
                    *(f32x4*)((float*)C + gm * ldc + (n0 + wc * 64 + jc * 32 + ep * 8 + c * 4)) = d;
                }
            }
        }
    }
}

// ---------- fused prep: x fp32->bf16 cast  +  W_{q,k,v} transpose-cast ----------
// blocks [0, nCast): vectorized cast of x. blocks [nCast, nCast+3072): W^T.
__global__ __launch_bounds__(256) void prep_fused(
    const float4* __restrict__ xin, unsigned short* __restrict__ xout, int n4, int nCast,
    const float* __restrict__ W0, const float* __restrict__ W1,
    const float* __restrict__ W2, unsigned short* __restrict__ wout, int n)
{
    const int tid = threadIdx.x;
    if ((int)blockIdx.x < nCast) {
        int i = blockIdx.x * 256 + tid;
        if (i >= n4) return;
        float4 v = xin[i];
        union { unsigned short u[4]; uint2 p; } o;
        o.u[0] = f2bf(v.x); o.u[1] = f2bf(v.y); o.u[2] = f2bf(v.z); o.u[3] = f2bf(v.w);
        *(uint2*)(xout + (long long)i * 4) = o.p;
        return;
    }
    const int bx = blockIdx.x - nCast;       // 0..3071
    const int wz = bx >> 10, rem = bx & 1023;
    const int wy = rem >> 5, wx = rem & 31;
    const float* in = (wz == 0) ? W0 : (wz == 1) ? W1 : W2;
    unsigned short* out = wout + (long long)wz * n * n;
    __shared__ float tile[32][33];
    const int tx = tid & 31, ty = tid >> 5;
    const int c0 = wx * 32, r0 = wy * 32;
#pragma unroll
    for (int i = 0; i < 4; i++)
        tile[ty + i * 8][tx] = in[(long long)(r0 + ty + i * 8) * n + c0 + tx];
    __syncthreads();
#pragma unroll
    for (int i = 0; i < 4; i++)
        out[(long long)(c0 + ty + i * 8) * n + r0 + tx] = f2bf(tile[tx][ty + i * 8]);
}

// ---------- causal softmax: S (bf16, B*T rows of T) -> P (bf16), vectorized ----------
__global__ __launch_bounds__(256) void causal_softmax_bf16(
    const unsigned short* __restrict__ S, unsigned short* __restrict__ P, int T)
{
    const int row = blockIdx.x;            // 0 .. B*T-1
    const int t   = row & (T - 1);
    const int L   = t + 1;
    const unsigned short* s = S + (long long)row * T;
    unsigned short* p = P + (long long)row * T;
    const int tid  = threadIdx.x;
    const int base = tid * 8;

    uint4 raw = *(const uint4*)(s + base);
    unsigned rr[4] = {raw.x, raw.y, raw.z, raw.w};
    float v[8];
#pragma unroll
    for (int k = 0; k < 4; k++) {
        union { unsigned u; float f; } a, b;
        a.u = (rr[k] & 0xFFFFu) << 16;
        b.u = rr[k] & 0xFFFF0000u;
        v[2 * k] = a.f; v[2 * k + 1] = b.f;
    }
    float mx = -3.0e38f;
#pragma unroll
    for (int k = 0; k < 8; k++) {
        if (base + k >= L) v[k] = -3.0e38f;
        mx = fmaxf(mx, v[k]);
    }
#pragma unroll
    for (int off = 32; off; off >>= 1) mx = fmaxf(mx, __shfl_xor(mx, off));
    __shared__ float red[4], red2[4];
    const int wid = tid >> 6, lid = tid & 63;
    if (lid == 0) red[wid] = mx;
    __syncthreads();
    mx = fmaxf(fmaxf(red[0], red[1]), fmaxf(red[2], red[3]));

    float sum = 0.f;
#pragma unroll
    for (int k = 0; k < 8; k++) { v[k] = __expf(v[k] - mx); sum += v[k]; }
#pragma unroll
    for (int off = 32; off; off >>= 1) sum += __shfl_xor(sum, off);
    if (lid == 0) red2[wid] = sum;
    __syncthreads();
    sum = red2[0] + red2[1] + red2[2] + red2[3];
    const float inv = 1.0f / sum;

    union { unsigned short u[8]; uint4 q; } o;
#pragma unroll
    for (int k = 0; k < 8; k++) o.u[k] = f2bf(v[k] * inv);
    *(uint4*)(p + base) = o.q;
}

// ---------- launch ----------
extern "C" void kernel_launch(void* const* d_in, const int* in_sizes, int n_in,
                              void* d_out, int out_size, void* d_ws, size_t ws_size,
                              hipStream_t stream)
{
    const int B = 4, T = 2048, C = 1024, D = 1024;
    const float* x  = (const float*)d_in[0];
    const float* Wq = (const float*)d_in[1];
    const float* Wk = (const float*)d_in[2];
    const float* Wv = (const float*)d_in[3];
    float* out = (float*)d_out;
    char* ws = (char*)d_ws;

    const size_t MB = 1ull << 20;
    unsigned short* Xbf   = (unsigned short*)(ws + 0);
    unsigned short* WqkvT = (unsigned short*)(ws + 16 * MB);
    unsigned short* QK    = (unsigned short*)(ws + 22 * MB);
    unsigned short* Vt    = (unsigned short*)(ws + 54 * MB);
    unsigned short* Sbf   = (unsigned short*)(ws + 70 * MB);
    unsigned short* P     = (unsigned short*)(ws + 0);

    const long long sX  = (long long)T * C;        // 2048*1024
    const long long sQK = (long long)T * 2 * D;    // 2048*2048
    const long long sVt = (long long)D * T;        // 1024*2048
    const long long sS  = (long long)T * T;        // 2048*2048
    const long long sO  = (long long)T * D;        // 2048*1024

    // 1) fused prep: x -> bf16 cast  +  W^T cast (one launch)
    {
        int n4 = B * T * C / 4;                    // 2,097,152
        int nCast = (n4 + 255) / 256;              // 8192
        prep_fused<<<dim3(nCast + 3072), dim3(256), 0, stream>>>(
            (const float4*)x, Xbf, n4, nCast, Wq, Wk, Wv, WqkvT, 1024);
    }
    // 2) fused QKV GEMM: Q,K -> QK (ldc 2048); V third -> Vt transposed (VFOLD)
    {
        dim3 g(384, 1, 4), b(256);
        gemm_bt<unsigned short, false, true, 1><<<g, b, 0, stream>>>(
            Xbf, WqkvT, QK, Vt, 2048, 3072, 1024, 1024, 1024, 2048,
            /*ldvt*/ T, /*nsplit*/ 2048, sX, 0, sQK, sVt, 1.0f);
    }
    // 3) S = Q K^T / 32 -> bf16, triangular-packed causal grid, z-pure XCD
    {
        dim3 g(136, 1, 4), b(256);
        gemm_bt<unsigned short, false, false, 2><<<g, b, 0, stream>>>(
            QK, QK + D, Sbf, nullptr, 2048, 2048, 1024, 2 * D, 2 * D, 2048,
            0, 0, sQK, sQK, sS, 0, 0.03125f);
    }
    // 4) causal softmax (bf16 -> bf16)
    {
        causal_softmax_bf16<<<dim3(B * T), dim3(256), 0, stream>>>(Sbf, P, T);
    }
    // 5) O = P V (K clamped causally, heavy-first within XCD), z-pure XCD
    {
        dim3 g(128, 1, 4), b(256);
        gemm_bt<float, true, false, 3><<<g, b, 0, stream>>>(
            P, Vt, out, nullptr, 2048, 1024, 2048, 2048, 2048, 1024,
            0, 0, sS, sVt, sO, 0, 1.0f);
    }
    (void)in_sizes; (void)n_in; (void)out_size; (void)ws_size;
}